// Round 11
// baseline (143.906 us; speedup 1.0000x reference)
//
#include <hip/hip_runtime.h>
#include <hip/hip_bf16.h>

// ---------------------------------------------------------------------------
// EuclideanDeconf: out[b,c] = (2*dot(x[b],W[c]) - ||x[b]||^2 - ||W[c]||^2) / D
// R17: fat waves. Nine structures (R8-R16) proved LDS/sync/occupancy/staging
// all null; the invariant was arithmetic intensity (<=8 MFMA per wave-tile,
// 1:1 MFMA:frag-load). R17: each wave owns 128x128 out = 4x4 fragments ->
// 16 MFMAs per 8 frag loads (2:1). Per SIMD per tile-step: ~1100cy matrix vs
// ~256cy vmem -> matrix pipe is the long pole for the first time.
// Fragment-major workspace (R16, HW-verified): tile (mt,kt) = 2048B at
// (mt*64+kt)*2048, lane l reads bytes l*32..+32 = its exact 32x32x64 fragment;
// loads are i32x8 derefs (2 coalesced dwordx4, contiguous tuples, no LDS, no
// barriers). PD=2 reg ring, counted WAITV(16). 256x256 block (4 waves 2x2),
// KSPLIT=4 -> grid (16,4,4)=256. fp8 partials (1/16) + reduce (R11-verified
// algebra, remapped to 4x4 geometry). acc 256 + ring 128 VGPR, 1 wave/SIMD.
// ---------------------------------------------------------------------------

typedef float f32x4 __attribute__((ext_vector_type(4)));
typedef float f32x2 __attribute__((ext_vector_type(2)));
typedef float f32x16 __attribute__((ext_vector_type(16)));
typedef int i32x4 __attribute__((ext_vector_type(4)));
typedef int i32x8 __attribute__((ext_vector_type(8)));

#define BDIM 4096
#define DDIM 4096
#define CDIM 1024
#define TM 256
#define TN 256
#define BK 64
#define KSPLIT 4
#define NIT ((DDIM / KSPLIT) / BK)   // 16
#define SCALE 32.0f
#define INV_SS (1.0f/1024.0f)
#define PSCALE 0.0625f               // partial pack scale (1/16)

#define WAITV(N) asm volatile("s_waitcnt vmcnt(" #N ")" ::: "memory")

// One WAVE per row: fp32 row -> fp8(e4m3, x SCALE) in FRAGMENT-MAJOR layout
// + fp32 sum-of-squares of the UNSCALED values. (R16, HW-verified.)
// Lane l covers k-floats [l*64, l*64+64) = k-tile kt=l of this row.
// Dest: base + (row>>5)*131072 + l*2048 + (row&31)*32 + {0,16,1024,1040}.
__global__ __launch_bounds__(256) void cvt_rowsq(
    const float* __restrict__ x, const float* __restrict__ W,
    unsigned char* __restrict__ xb, unsigned char* __restrict__ wb,
    float* __restrict__ xsq, float* __restrict__ wsq)
{
    const int lane = threadIdx.x & 63;
    const int row = blockIdx.x * 4 + (threadIdx.x >> 6);

    const float* src;
    unsigned char* dstb;
    float* sq;
    int r;
    if (row < BDIM) {
        src = x + (size_t)row * DDIM;
        dstb = xb; r = row;
        sq = xsq + row;
    } else {
        r = row - BDIM;
        src = W + (size_t)r * DDIM;
        dstb = wb;
        sq = wsq + r;
    }

    const float4* s4 = (const float4*)src;
    float a = 0.f;
    unsigned int pk[16];
    #pragma unroll
    for (int u = 0; u < 16; ++u) {
        float4 f = s4[lane * 16 + u];
        a += f.x * f.x + f.y * f.y + f.z * f.z + f.w * f.w;
        unsigned int p = 0;
        p = __builtin_amdgcn_cvt_pk_fp8_f32(f.x * SCALE, f.y * SCALE, p, false);
        p = __builtin_amdgcn_cvt_pk_fp8_f32(f.z * SCALE, f.w * SCALE, p, true);
        pk[u] = p;
    }
    unsigned char* db = dstb + (size_t)(r >> 5) * 131072
                      + (size_t)lane * 2048 + (r & 31) * 32;
    i32x4 v0 = {(int)pk[0], (int)pk[1], (int)pk[2], (int)pk[3]};
    i32x4 v1 = {(int)pk[4], (int)pk[5], (int)pk[6], (int)pk[7]};
    i32x4 v2 = {(int)pk[8], (int)pk[9], (int)pk[10], (int)pk[11]};
    i32x4 v3 = {(int)pk[12], (int)pk[13], (int)pk[14], (int)pk[15]};
    *(i32x4*)(db)        = v0;
    *(i32x4*)(db + 16)   = v1;
    *(i32x4*)(db + 1024) = v2;
    *(i32x4*)(db + 1040) = v3;

    #pragma unroll
    for (int off = 32; off > 0; off >>= 1) a += __shfl_down(a, off);
    if (lane == 0) *sq = a;
}

// --- GEMM, LDS-free, fat-wave 4x4 ---
__device__ __forceinline__ i32x8 ld8(const unsigned char* p) {
    return *(const i32x8*)p;
}

#define MXMFMA(A, Bv, C)                                                  \
    __builtin_amdgcn_mfma_scale_f32_32x32x64_f8f6f4(                      \
        (A), (Bv), (C), 0, 0, 0, 0x7F7F7F7F, 0, 0x7F7F7F7F)

struct FragT { i32x8 a[4]; i32x8 b[4]; };   // one K-tile of operands (64 VGPR)

__global__ __launch_bounds__(256) void gemm_eucl(
    const unsigned char* __restrict__ xb,   // [B/32][64][64][32] fp8 frag-major
    const unsigned char* __restrict__ wb,   // [C/32][64][64][32] fp8 frag-major
    unsigned int* __restrict__ part)        // [KSPLIT][64 blk][16 f][4 g][256]
{
    const int tid = threadIdx.x;
    const int lane = tid & 63;
    const int w = tid >> 6;                 // wave 0..3
    const int wr = w >> 1;                  // 0..1  (M half: 128 rows)
    const int wc = w & 1;                   // 0..1  (N half: 128 rows)

    // wave's frag-tile origins; K-slice base folded into the pointer
    const int mt0 = blockIdx.x * 8 + wr * 4;
    const int nt0 = blockIdx.y * 8 + wc * 4;
    const size_t kof = (size_t)blockIdx.z * NIT * 2048;
    const unsigned char* pA[4];
    const unsigned char* pB[4];
    #pragma unroll
    for (int i = 0; i < 4; ++i) {
        pA[i] = xb + (size_t)(mt0 + i) * 131072 + kof + (size_t)lane * 32;
        pB[i] = wb + (size_t)(nt0 + i) * 131072 + kof + (size_t)lane * 32;
    }

#define LOADF(S, t)                                                       \
    do {                                                                  \
        _Pragma("unroll")                                                 \
        for (int i = 0; i < 4; ++i) {                                     \
            (S).a[i] = ld8(pA[i] + (size_t)(t) * 2048);                   \
            (S).b[i] = ld8(pB[i] + (size_t)(t) * 2048);                   \
        }                                                                 \
    } while (0)

    f32x16 acc[16] = {};   // acc[i*4+j]

#define COMPUTE(S)                                                       \
    do {                                                                 \
        __builtin_amdgcn_s_setprio(1);                                   \
        _Pragma("unroll")                                                \
        for (int i = 0; i < 4; ++i)                                      \
            _Pragma("unroll")                                            \
            for (int j = 0; j < 4; ++j)                                  \
                acc[i * 4 + j] = MXMFMA((S).a[i], (S).b[j], acc[i * 4 + j]); \
        __builtin_amdgcn_s_setprio(0);                                   \
    } while (0)

    FragT S[2];
    // prologue: tiles 0,1 in flight (32 dwordx4)
    LOADF(S[0], 0);
    LOADF(S[1], 1);

    // main loop: WAITV(16) retires tile t's 16 loads (FIFO); t+1 flying.
    #pragma unroll
    for (int t = 0; t < NIT - 2; ++t) {
        WAITV(16);
        COMPUTE(S[t & 1]);
        LOADF(S[t & 1], t + 2);
    }
    WAITV(16); COMPUTE(S[(NIT - 2) & 1]);   // t=14
    WAITV(0);  COMPUTE(S[(NIT - 1) & 1]);   // t=15

    // ---- fp8 partials, scale 1/16: 64 uints/thread, coalesced ----
    const int bb = blockIdx.x * 4 + blockIdx.y;          // 0..63
    unsigned int* p = part + ((size_t)blockIdx.z * 64 + bb) * (64 * 256);
    #pragma unroll
    for (int f = 0; f < 16; ++f)
        #pragma unroll
        for (int g = 0; g < 4; ++g) {
            unsigned int pk = 0;
            pk = __builtin_amdgcn_cvt_pk_fp8_f32(
                acc[f][g * 4 + 0] * PSCALE, acc[f][g * 4 + 1] * PSCALE, pk, false);
            pk = __builtin_amdgcn_cvt_pk_fp8_f32(
                acc[f][g * 4 + 2] * PSCALE, acc[f][g * 4 + 3] * PSCALE, pk, true);
            p[(f * 4 + g) * 256 + tid] = pk;
        }
#undef LOADF
#undef COMPUTE
}

// 512 blocks x 256 thr; reduce block = 8 (f,g)-units of one gemm block.
// 32x32 C/D layout: col = lane&31, row = (reg&3)+8*(reg>>2)+4*(lane>>5);
// packed grp g holds regs 4g..4g+3 -> row = r + 8g + 4*(lane>>5).
// f = i*4+j; wave origin (wr*128, wc*128); frag origin (+i*32, +j*32).
__global__ __launch_bounds__(256) void reduce_out(
    const unsigned int* __restrict__ part, const float* __restrict__ xsq,
    const float* __restrict__ wsq, float* __restrict__ out)
{
    const int bid = blockIdx.x;           // 0..511
    const int bb = bid >> 3;              // gemm block 0..63 (bx*4 + by)
    const int oct = bid & 7;              // 8 fg-units each
    const int t = threadIdx.x;
    const int lane = t & 63;
    const int w = t >> 6;                 // gemm wave 0..3
    const int wr = w >> 1, wc = w & 1;
    const int bm = (bb >> 2) * TM, bn = (bb & 3) * TN;
    const size_t sl = (size_t)64 * 64 * 256;     // uints per z-slice
    const float c1 = 2.0f * 16.0f * INV_SS / (float)DDIM;  // 16 = 1/PSCALE
    const float c2 = 1.0f / (float)DDIM;

    #pragma unroll
    for (int ff = 0; ff < 8; ++ff) {
        const int fg = oct * 8 + ff;      // 0..63
        const int f = fg >> 2;            // 0..15
        const int g = fg & 3;
        size_t o = ((size_t)bb * 64 + fg) * 256 + t;
        f32x2 s01 = {0.f, 0.f}, s23 = {0.f, 0.f};
        #pragma unroll
        for (int z = 0; z < KSPLIT; ++z) {
            unsigned int u = part[o + (size_t)z * sl];
            s01 += __builtin_amdgcn_cvt_pk_f32_fp8(u, false);
            s23 += __builtin_amdgcn_cvt_pk_f32_fp8(u, true);
        }
        const int i = f >> 2, j = f & 3;
        const int gn = bn + wc * 128 + j * 32 + (lane & 31);
        const float wv = wsq[gn];
        const int gm0 = bm + wr * 128 + i * 32 + g * 8 + (lane >> 5) * 4;
        float sv[4] = {s01.x, s01.y, s23.x, s23.y};
        #pragma unroll
        for (int r = 0; r < 4; ++r) {
            out[(size_t)(gm0 + r) * CDIM + gn] = sv[r] * c1 - (xsq[gm0 + r] + wv) * c2;
        }
    }
}

// --- Fallback: naive fp32 (any ws) ---
__global__ void fallback_kernel(const float* __restrict__ x, const float* __restrict__ W,
                                float* __restrict__ out)
{
    int c = blockIdx.x * blockDim.x + threadIdx.x;
    int b = blockIdx.y;
    if (c >= CDIM) return;
    const float* xr = x + (size_t)b * DDIM;
    const float* wr = W + (size_t)c * DDIM;
    float xs = 0.f, ws = 0.f, cr = 0.f;
    for (int d = 0; d < DDIM; ++d) {
        float xv = xr[d], wv = wr[d];
        xs += xv * xv; ws += wv * wv; cr += xv * wv;
    }
    out[(size_t)b * CDIM + c] = (2.0f * cr - xs - ws) / (float)DDIM;
}

extern "C" void kernel_launch(void* const* d_in, const int* in_sizes, int n_in,
                              void* d_out, int out_size, void* d_ws, size_t ws_size,
                              hipStream_t stream) {
    const float* x = (const float*)d_in[0];   // [B, D] fp32
    const float* W = (const float*)d_in[1];   // [C, D] fp32
    float* out = (float*)d_out;               // [B, C] fp32

    size_t need = (size_t)(BDIM + CDIM) * DDIM                 // fp8 inputs 20 MB
                + (size_t)(BDIM + CDIM) * sizeof(float)        // norms
                + (size_t)KSPLIT * BDIM * CDIM;                // fp8 partials 16 MB
    if (ws_size < need) {
        fallback_kernel<<<dim3(CDIM / 256, BDIM), 256, 0, stream>>>(x, W, out);
        return;
    }

    unsigned char* xb = (unsigned char*)d_ws;              // 16 MB (frag-major)
    unsigned char* wb = xb + (size_t)BDIM * DDIM;          // 4 MB (frag-major)
    float* xsq = (float*)(wb + (size_t)CDIM * DDIM);       // 16 KB
    float* wsq = xsq + BDIM;                               // 4 KB
    unsigned int* part = (unsigned int*)(wsq + CDIM);      // 16 MB

    cvt_rowsq<<<(BDIM + CDIM) / 4, 256, 0, stream>>>(x, W, xb, wb, xsq, wsq);
    gemm_eucl<<<dim3(BDIM / TM, CDIM / TN, KSPLIT), 256, 0, stream>>>(xb, wb, part);
    reduce_out<<<512, 256, 0, stream>>>(part, xsq, wsq, out);
}

// Round 12
// 133.676 us; speedup vs baseline: 1.0765x; 1.0765x over previous
//
#include <hip/hip_runtime.h>
#include <hip/hip_bf16.h>

// ---------------------------------------------------------------------------
// EuclideanDeconf: out[b,c] = (2*dot(x[b],W[c]) - ||x[b]||^2 - ||W[c]||^2) / D
// R18: R14 (132.6us best) with HALF the sync events. Ten structures (R8-R17)
// pinned the gemm at 30-43us across every axis (LDS/reg/none staging, 0-8
// barriers, occupancy 1-3, intensity 0.5-2.0); the invariant is ~250-500cy of
// per-tile sync+issue machinery. R18 keeps R14's verified machinery byte-for-
// byte in spirit and (a) doubles BK to 128 -> 32 tiles instead of 64 (halves
// WAITV/barrier/stage-group count; LDS ring 4x32KB=128KB, occupancy unchanged
// at 1 block/CU by grid), (b) issues STAGE(t+2) BEFORE WAITV+BAR (safe: all
// waves passed BAR(t-1) => all tile-(t-2) ds_reads complete; buf (t+2)&3 ==
// (t-2)&3), overlapping DMA issue with the wait. Swizzle re-derived for
// 8-chunk rows: slot = chunk ^ (row&7); source pre-swz ((t&7)^((t>>3)&7));
// read slot-pairs differ in bit0 (cb even) -> conflict-floor both sides.
// KSPLIT=1 + fused epilogue kept. 128x128xBK128, 256 thr, grid (32,8)=256.
// ---------------------------------------------------------------------------

typedef float f32x4 __attribute__((ext_vector_type(4)));
typedef float f32x2 __attribute__((ext_vector_type(2)));
typedef float f32x16 __attribute__((ext_vector_type(16)));
typedef int i32x4 __attribute__((ext_vector_type(4)));
typedef int i32x8 __attribute__((ext_vector_type(8)));

#define BDIM 4096
#define DDIM 4096
#define CDIM 1024
#define TM 128
#define TN 128
#define BK 128
#define NIT (DDIM / BK)              // 32
#define SCALE 32.0f
#define INV_SS (1.0f/1024.0f)

#define WAITV(N) asm volatile("s_waitcnt vmcnt(" #N ")" ::: "memory")
#define BAR()    __builtin_amdgcn_s_barrier()

// One WAVE per row: fp32 row -> fp8(e4m3, x SCALE) row-major + fp32
// sum-of-squares of the UNSCALED values. (R14 version, HW-verified.)
__global__ __launch_bounds__(256) void cvt_rowsq(
    const float* __restrict__ x, const float* __restrict__ W,
    unsigned char* __restrict__ xb, unsigned char* __restrict__ wb,
    float* __restrict__ xsq, float* __restrict__ wsq)
{
    const int lane = threadIdx.x & 63;
    const int row = blockIdx.x * 4 + (threadIdx.x >> 6);

    const float* src;
    unsigned char* dst;
    float* sq;
    if (row < BDIM) {
        src = x + (size_t)row * DDIM;
        dst = xb + (size_t)row * DDIM;
        sq = xsq + row;
    } else {
        int r = row - BDIM;
        src = W + (size_t)r * DDIM;
        dst = wb + (size_t)r * DDIM;
        sq = wsq + r;
    }

    const float4* s4 = (const float4*)src;
    unsigned int* d4 = (unsigned int*)dst;
    float a = 0.f;
    #pragma unroll
    for (int s = 0; s < DDIM / 4 / 64; ++s) {
        float4 f = s4[lane + 64 * s];
        a += f.x * f.x + f.y * f.y + f.z * f.z + f.w * f.w;
        unsigned int p = 0;
        p = __builtin_amdgcn_cvt_pk_fp8_f32(f.x * SCALE, f.y * SCALE, p, false);
        p = __builtin_amdgcn_cvt_pk_fp8_f32(f.z * SCALE, f.w * SCALE, p, true);
        d4[lane + 64 * s] = p;
    }
    #pragma unroll
    for (int off = 32; off > 0; off >>= 1) a += __shfl_down(a, off);
    if (lane == 0) *sq = a;
}

// --- GEMM + fused epilogue ---
// LDS: 4 bufs, buf q at q*32768: A[128][128] fp8 at +0, B[128][128] at +16384.
// Swizzle: 16B chunk (row m, chunk c in 0..7) at slot (m, c ^ (m&7)).
// Staging: 4 issue-groups per operand (32 rows each). Thread t covers row
// i*32+(t>>3), slot t&7 <- global chunk (t&7)^((t>>3)&7) [row&7 == (t>>3)&7
// == lane>>3, wave-independent]. DMA dest wave-uniform sm+q*32768(+16384)
// +i*4096+w*1024; writes lane*16 -> row-major [32][8] per group. 8 threads
// of a row read a permutation of two 64B lines -> fully coalesced.
// Frag reads: lane l row (l&31)+{0,32}, k-sub s chunks cb=s*4+(l>>5)*2,cb+1;
// slot = chunk ^ (l&7); slot-pair differs in bit0 -> byte ^16. 8-lane groups
// hit 8 distinct bank-starts -> 2x floor (conflict-free).

__device__ __forceinline__ i32x8 cat8(i32x4 lo, i32x4 hi) {
    return __builtin_shufflevector(lo, hi, 0, 1, 2, 3, 4, 5, 6, 7);
}

#define MXMFMA(A, Bv, C)                                                  \
    __builtin_amdgcn_mfma_scale_f32_32x32x64_f8f6f4(                      \
        (A), (Bv), (C), 0, 0, 0, 0x7F7F7F7F, 0, 0x7F7F7F7F)

#define GLOAD16(gp, lp)                                                   \
    __builtin_amdgcn_global_load_lds(                                     \
        (const __attribute__((address_space(1))) void*)(gp),              \
        (__attribute__((address_space(3))) void*)(lp), 16, 0, 0)

__global__ __launch_bounds__(256) void gemm_eucl(
    const unsigned char* __restrict__ xb,   // [B, D] fp8 row-major
    const unsigned char* __restrict__ wb,   // [C, D] fp8 row-major
    const float* __restrict__ xsq, const float* __restrict__ wsq,
    float* __restrict__ out)                // [B, C] fp32
{
    __shared__ unsigned char sm[4 * 32768];   // 128 KB

    const int tid = threadIdx.x;
    const int lane = tid & 63;
    const int w = tid >> 6;                 // wave 0..3
    const int wr = w >> 1;                  // 0..1  (M half: 64 rows)
    const int wc = w & 1;                   // 0..1  (N half: 64 rows)
    const int bm = blockIdx.x * TM;
    const int bn = blockIdx.y * TN;

    // ---- staging: per-lane pre-swizzled global sources (coalesced) ----
    const int sr = tid >> 3;                              // row in 32-group? 0..31
    const int sc = ((tid & 7) ^ ((tid >> 3) & 7)) * 16;   // source chunk byte
    const unsigned char* gA[4];
    const unsigned char* gB[4];
    #pragma unroll
    for (int i = 0; i < 4; ++i) {
        gA[i] = xb + (size_t)(bm + i * 32 + sr) * DDIM + sc;
        gB[i] = wb + (size_t)(bn + i * 32 + sr) * DDIM + sc;
    }

#define STAGE(q, t)                                                       \
    do {                                                                  \
        _Pragma("unroll")                                                 \
        for (int i = 0; i < 4; ++i)                                       \
            GLOAD16(gA[i] + (size_t)(t) * BK,                             \
                    sm + (q) * 32768 + i * 4096 + w * 1024);              \
        _Pragma("unroll")                                                 \
        for (int i = 0; i < 4; ++i)                                       \
            GLOAD16(gB[i] + (size_t)(t) * BK,                             \
                    sm + (q) * 32768 + 16384 + i * 4096 + w * 1024);      \
    } while (0)

    // ---- fragment read bases (swizzled) ----
    const int rl = lane & 31;
    const int sw = lane & 7;
    const int kb = (lane >> 5) * 2;          // 0 or 2
    const int rowA = (wr * 64 + rl) * BK;    // byte row base (A)
    const int rowB = (wc * 64 + rl) * BK;
    // k-sub 0: chunks kb, kb+1 ; k-sub 1: chunks kb+4, kb+5 (kb even)
    const int sl00 = (kb ^ sw) * 16;
    const int sl01 = ((kb + 1) ^ sw) * 16;
    const int sl10 = ((kb + 4) ^ sw) * 16;
    const int sl11 = ((kb + 5) ^ sw) * 16;
    const unsigned char* aP00 = sm + rowA + sl00;
    const unsigned char* aP01 = sm + rowA + sl01;
    const unsigned char* aP10 = sm + rowA + sl10;
    const unsigned char* aP11 = sm + rowA + sl11;
    const unsigned char* bP00 = sm + 16384 + rowB + sl00;
    const unsigned char* bP01 = sm + 16384 + rowB + sl01;
    const unsigned char* bP10 = sm + 16384 + rowB + sl10;
    const unsigned char* bP11 = sm + 16384 + rowB + sl11;
    // frag i=1 (rows +32): +32*BK = +4096; (row+32)&7 == row&7, swizzle same.

    f32x16 acc[4] = {};   // [i 0..1][j 0..1] -> acc[i*2+j]

#define COMPUTE(qo)                                                       \
    do {                                                                  \
        /* k-sub 0 */                                                     \
        i32x8 fb0 = cat8(*(const i32x4*)(bP00 + (qo)),                    \
                         *(const i32x4*)(bP01 + (qo)));                   \
        i32x8 fb1 = cat8(*(const i32x4*)(bP00 + (qo) + 4096),             \
                         *(const i32x4*)(bP01 + (qo) + 4096));            \
        i32x8 fa0 = cat8(*(const i32x4*)(aP00 + (qo)),                    \
                         *(const i32x4*)(aP01 + (qo)));                   \
        i32x8 fa1 = cat8(*(const i32x4*)(aP00 + (qo) + 4096),             \
                         *(const i32x4*)(aP01 + (qo) + 4096));            \
        __builtin_amdgcn_s_setprio(1);                                    \
        acc[0] = MXMFMA(fa0, fb0, acc[0]);                                \
        acc[1] = MXMFMA(fa0, fb1, acc[1]);                                \
        acc[2] = MXMFMA(fa1, fb0, acc[2]);                                \
        acc[3] = MXMFMA(fa1, fb1, acc[3]);                                \
        __builtin_amdgcn_s_setprio(0);                                    \
        /* k-sub 1 */                                                     \
        fb0 = cat8(*(const i32x4*)(bP10 + (qo)),                          \
                   *(const i32x4*)(bP11 + (qo)));                         \
        fb1 = cat8(*(const i32x4*)(bP10 + (qo) + 4096),                   \
                   *(const i32x4*)(bP11 + (qo) + 4096));                  \
        fa0 = cat8(*(const i32x4*)(aP10 + (qo)),                          \
                   *(const i32x4*)(aP11 + (qo)));                         \
        fa1 = cat8(*(const i32x4*)(aP10 + (qo) + 4096),                   \
                   *(const i32x4*)(aP11 + (qo) + 4096));                  \
        __builtin_amdgcn_s_setprio(1);                                    \
        acc[0] = MXMFMA(fa0, fb0, acc[0]);                                \
        acc[1] = MXMFMA(fa0, fb1, acc[1]);                                \
        acc[2] = MXMFMA(fa1, fb0, acc[2]);                                \
        acc[3] = MXMFMA(fa1, fb1, acc[3]);                                \
        __builtin_amdgcn_s_setprio(0);                                    \
    } while (0)

    // ---- prologue: tiles 0,1 staged into bufs 0,1 (16 loads in flight) ----
    STAGE(0, 0);
    STAGE(1, 1);

    // main loop: stage t+2 FIRST (off critical path; buf (t+2)&3 == (t-2)&3,
    // reads complete before all waves' BAR(t-1)); WAITV(16) retires tile t's
    // 8 loads (in-flight: 24 after stage), keeps t+1,t+2 flying.
    #pragma unroll 4
    for (int t = 0; t < NIT - 2; ++t) {
        STAGE((t + 2) & 3, t + 2);
        WAITV(16);
        BAR();
        COMPUTE((t & 3) * 32768);
    }
    // peeled tail (no staging)
    WAITV(8); BAR(); COMPUTE(((NIT - 2) & 3) * 32768);
    WAITV(0); BAR(); COMPUTE(((NIT - 1) & 3) * 32768);

    // ---- fused epilogue ----
    // 32x32 C/D layout: col = lane&31, row = (reg&3)+8*(reg>>2)+4*(lane>>5).
    const float c1m = 2.0f * INV_SS / (float)DDIM;
    const float c2 = 1.0f / (float)DDIM;
    const int gn0 = bn + wc * 64 + (lane & 31);
    const int gm_b = bm + wr * 64 + (lane >> 5) * 4;
    const float wv0 = wsq[gn0];
    const float wv1 = wsq[gn0 + 32];
    #pragma unroll
    for (int i = 0; i < 2; ++i)
        #pragma unroll
        for (int g = 0; g < 4; ++g)
            #pragma unroll
            for (int r = 0; r < 4; ++r) {
                const int gm = gm_b + i * 32 + g * 8 + r;
                const float xs = xsq[gm];
                out[(size_t)gm * CDIM + gn0] =
                    acc[i * 2 + 0][g * 4 + r] * c1m - (xs + wv0) * c2;
                out[(size_t)gm * CDIM + gn0 + 32] =
                    acc[i * 2 + 1][g * 4 + r] * c1m - (xs + wv1) * c2;
            }
#undef STAGE
#undef COMPUTE
}

// --- Fallback: naive fp32 (any ws) ---
__global__ void fallback_kernel(const float* __restrict__ x, const float* __restrict__ W,
                                float* __restrict__ out)
{
    int c = blockIdx.x * blockDim.x + threadIdx.x;
    int b = blockIdx.y;
    if (c >= CDIM) return;
    const float* xr = x + (size_t)b * DDIM;
    const float* wr = W + (size_t)c * DDIM;
    float xs = 0.f, ws = 0.f, cr = 0.f;
    for (int d = 0; d < DDIM; ++d) {
        float xv = xr[d], wv = wr[d];
        xs += xv * xv; ws += wv * wv; cr += xv * wv;
    }
    out[(size_t)b * CDIM + c] = (2.0f * cr - xs - ws) / (float)DDIM;
}

extern "C" void kernel_launch(void* const* d_in, const int* in_sizes, int n_in,
                              void* d_out, int out_size, void* d_ws, size_t ws_size,
                              hipStream_t stream) {
    const float* x = (const float*)d_in[0];   // [B, D] fp32
    const float* W = (const float*)d_in[1];   // [C, D] fp32
    float* out = (float*)d_out;               // [B, C] fp32

    size_t need = (size_t)(BDIM + CDIM) * DDIM                 // fp8 inputs 20 MB
                + (size_t)(BDIM + CDIM) * sizeof(float);       // norms
    if (ws_size < need) {
        fallback_kernel<<<dim3(CDIM / 256, BDIM), 256, 0, stream>>>(x, W, out);
        return;
    }

    unsigned char* xb = (unsigned char*)d_ws;              // 16 MB
    unsigned char* wb = xb + (size_t)BDIM * DDIM;          // 4 MB
    float* xsq = (float*)(wb + (size_t)CDIM * DDIM);       // 16 KB
    float* wsq = xsq + BDIM;                               // 4 KB

    cvt_rowsq<<<(BDIM + CDIM) / 4, 256, 0, stream>>>(x, W, xb, wb, xsq, wsq);
    gemm_eucl<<<dim3(BDIM / TM, CDIM / TN), 256, 0, stream>>>(xb, wb, xsq, wsq, out);
}